// Round 1
// baseline (365.123 us; speedup 1.0000x reference)
//
#include <hip/hip_runtime.h>
#include <stdint.h>

// EventAwareAttention: B=8, S=2048, H=DK=512
// d_out = [context fp32 (8*2048*512)] ++ [attn fp32 (8*2048*2048)]
// d_ws requirement: 5 * 8*2048*512 * 2 bytes = 83,886,080 bytes (~84 MB)
//   layout: Qhi | Qlo | Khi | Klo | Vt   (each 16384x512 bf16; Vt is [b][h][s])
//   attn-bf16 copy (16384x2048) aliases Qhi..Klo after they are dead.

#define Bn 8
#define Sn 2048
#define Hn 512
#define BM 128
#define BN 128
#define BKk 64

typedef unsigned short u16;
typedef __attribute__((ext_vector_type(8))) short bf16x8;
typedef __attribute__((ext_vector_type(4))) float f32x4;
typedef __attribute__((ext_vector_type(8))) unsigned short us8;
typedef __attribute__((ext_vector_type(4))) unsigned short us4;

__device__ __forceinline__ u16 f2bf(float x) {
  union { float f; uint32_t u; } c;
  c.f = x;
  uint32_t u = c.u;
  return (u16)((u + 0x7FFFu + ((u >> 16) & 1u)) >> 16);   // RNE
}
__device__ __forceinline__ float bf2f(u16 h) {
  union { uint32_t u; float f; } c;
  c.u = ((uint32_t)h) << 16;
  return c.f;
}
__device__ __forceinline__ f32x4 mfma16(bf16x8 a, bf16x8 b, f32x4 c) {
  return __builtin_amdgcn_mfma_f32_16x16x32_bf16(a, b, c, 0, 0, 0);
}
__device__ __forceinline__ void g2l16(const void* g, void* l) {
  __builtin_amdgcn_global_load_lds(
      (const __attribute__((address_space(1))) void*)g,
      (__attribute__((address_space(3))) void*)l,
      16, 0, 0);
}

// ---------------------------------------------------------------------------
// K1: QKV projection. C[M=16384, N=12*128] = X[M,512] . W[N,512]^T + bias
// 3-MFMA bf16 split for full accuracy. Q/K stored as hi/lo bf16 pairs; V
// stored bf16 transposed per batch: Vt[b][o][s].
// ---------------------------------------------------------------------------
__global__ __launch_bounds__(256) void k1_proj(
    const float* __restrict__ X,
    const float* __restrict__ Wq, const float* __restrict__ bq,
    const float* __restrict__ Wk, const float* __restrict__ bk,
    const float* __restrict__ Wv, const float* __restrict__ bv,
    u16* __restrict__ Qhi, u16* __restrict__ Qlo,
    u16* __restrict__ Khi, u16* __restrict__ Klo,
    u16* __restrict__ Vt) {
  __shared__ u16 lAhi[BM * BKk], lAlo[BM * BKk];
  __shared__ u16 lBhi[BM * BKk], lBlo[BM * BKk];
  const int t = threadIdx.x;
  const int lane = t & 63;
  const int wid = t >> 6;
  const int wr = wid >> 1, wc = wid & 1;
  const int tn = blockIdx.x;          // 0..11: [Q0..3 K0..3 V0..3]
  const int m0 = blockIdx.y * BM;
  const int mat = tn >> 2;
  const int o0 = (tn & 3) * BN;
  const float* Wsel = (mat == 0) ? Wq : ((mat == 1) ? Wk : Wv);
  const float* bsel = (mat == 0) ? bq : ((mat == 1) ? bk : bv);

  f32x4 acc[4][4];
  const f32x4 fz = {0.f, 0.f, 0.f, 0.f};
#pragma unroll
  for (int m = 0; m < 4; ++m)
#pragma unroll
    for (int n = 0; n < 4; ++n) acc[m][n] = fz;

  for (int k0 = 0; k0 < Hn; k0 += BKk) {
    __syncthreads();
#pragma unroll
    for (int i = 0; i < 4; ++i) {
      const int c = t + 256 * i;      // 16B-chunk id, 0..1023
      const int row = c >> 3;
      const int col8 = c & 7;
      const int dst = row * BKk + ((col8 ^ (row & 7)) << 3);  // XOR swizzle
      {
        const float* g = X + (size_t)(m0 + row) * Hn + k0 + (col8 << 3);
        float4 v0 = *(const float4*)g;
        float4 v1 = *(const float4*)(g + 4);
        float xs[8] = {v0.x, v0.y, v0.z, v0.w, v1.x, v1.y, v1.z, v1.w};
        us8 h, l;
#pragma unroll
        for (int j = 0; j < 8; ++j) {
          u16 hh = f2bf(xs[j]);
          h[j] = hh;
          l[j] = f2bf(xs[j] - bf2f(hh));
        }
        *(us8*)&lAhi[dst] = h;
        *(us8*)&lAlo[dst] = l;
      }
      {
        const float* g = Wsel + (size_t)(o0 + row) * Hn + k0 + (col8 << 3);
        float4 v0 = *(const float4*)g;
        float4 v1 = *(const float4*)(g + 4);
        float xs[8] = {v0.x, v0.y, v0.z, v0.w, v1.x, v1.y, v1.z, v1.w};
        us8 h, l;
#pragma unroll
        for (int j = 0; j < 8; ++j) {
          u16 hh = f2bf(xs[j]);
          h[j] = hh;
          l[j] = f2bf(xs[j] - bf2f(hh));
        }
        *(us8*)&lBhi[dst] = h;
        *(us8*)&lBlo[dst] = l;
      }
    }
    __syncthreads();
#pragma unroll
    for (int ks = 0; ks < 2; ++ks) {
      bf16x8 ah[4], al[4], bh[4], bl[4];
#pragma unroll
      for (int m = 0; m < 4; ++m) {
        const int row = wr * 64 + m * 16 + (lane & 15);
        const int col8 = ks * 4 + (lane >> 4);
        const int off = row * BKk + ((col8 ^ (row & 7)) << 3);
        ah[m] = *(const bf16x8*)&lAhi[off];
        al[m] = *(const bf16x8*)&lAlo[off];
      }
#pragma unroll
      for (int n = 0; n < 4; ++n) {
        const int row = wc * 64 + n * 16 + (lane & 15);
        const int col8 = ks * 4 + (lane >> 4);
        const int off = row * BKk + ((col8 ^ (row & 7)) << 3);
        bh[n] = *(const bf16x8*)&lBhi[off];
        bl[n] = *(const bf16x8*)&lBlo[off];
      }
#pragma unroll
      for (int m = 0; m < 4; ++m)
#pragma unroll
        for (int n = 0; n < 4; ++n) {
          acc[m][n] = mfma16(ah[m], bh[n], acc[m][n]);
          acc[m][n] = mfma16(ah[m], bl[n], acc[m][n]);
          acc[m][n] = mfma16(al[m], bh[n], acc[m][n]);
        }
    }
  }
  // epilogue
#pragma unroll
  for (int n = 0; n < 4; ++n) {
    const int o = o0 + wc * 64 + n * 16 + (lane & 15);
    const float bias = bsel[o];
#pragma unroll
    for (int m = 0; m < 4; ++m) {
      const int ib = m0 + wr * 64 + m * 16 + ((lane >> 4) << 2);
      if (mat < 2) {
        u16* Hi = (mat == 0) ? Qhi : Khi;
        u16* Lo = (mat == 0) ? Qlo : Klo;
#pragma unroll
        for (int r = 0; r < 4; ++r) {
          const float v = acc[m][n][r] + bias;
          const u16 hh = f2bf(v);
          Hi[(size_t)(ib + r) * Hn + o] = hh;
          Lo[(size_t)(ib + r) * Hn + o] = f2bf(v - bf2f(hh));
        }
      } else {
        const int bb = ib >> 11, s = ib & 2047;
        us4 p;
#pragma unroll
        for (int r = 0; r < 4; ++r) p[r] = f2bf(acc[m][n][r] + bias);
        *(us4*)&Vt[((size_t)bb * Hn + o) * Sn + s] = p;
      }
    }
  }
}

// ---------------------------------------------------------------------------
// K2: scores[b] = (Q[b] . K[b]^T) * shape_ratio / sqrt(512), fp32 -> d_out.
// 3-MFMA split; staging via global_load_lds w=16 with pre-swizzled source.
// ---------------------------------------------------------------------------
__global__ __launch_bounds__(256) void k2_scores(
    const u16* __restrict__ Qhi, const u16* __restrict__ Qlo,
    const u16* __restrict__ Khi, const u16* __restrict__ Klo,
    const float* __restrict__ shape_ratio,
    float* __restrict__ Sout) {
  __shared__ u16 lAhi[BM * BKk], lAlo[BM * BKk];
  __shared__ u16 lBhi[BM * BKk], lBlo[BM * BKk];
  const int t = threadIdx.x;
  const int lane = t & 63;
  const int wid = t >> 6;
  const int wr = wid >> 1, wc = wid & 1;
  const int b = blockIdx.z;
  const int n0 = blockIdx.x * BN;
  const int m0 = blockIdx.y * BM;
  const size_t qrow0 = (size_t)b * Sn + m0;
  const size_t krow0 = (size_t)b * Sn + n0;

  f32x4 acc[4][4];
  const f32x4 fz = {0.f, 0.f, 0.f, 0.f};
#pragma unroll
  for (int m = 0; m < 4; ++m)
#pragma unroll
    for (int n = 0; n < 4; ++n) acc[m][n] = fz;

  const int srow = lane >> 3;                     // row within 8-row chunk
  const int scol = ((lane & 7) ^ srow) << 3;      // pre-swizzled source col

  for (int k0 = 0; k0 < Hn; k0 += BKk) {
    __syncthreads();
#pragma unroll
    for (int j = 0; j < 4; ++j) {
      const int ci = wid * 4 + j;                 // 1KB chunk id 0..15
      const int row = ci * 8 + srow;
      const size_t ga = (qrow0 + row) * Hn + k0 + scol;
      const size_t gb = (krow0 + row) * Hn + k0 + scol;
      g2l16(Qhi + ga, &lAhi[ci * 512]);
      g2l16(Qlo + ga, &lAlo[ci * 512]);
      g2l16(Khi + gb, &lBhi[ci * 512]);
      g2l16(Klo + gb, &lBlo[ci * 512]);
    }
    __syncthreads();
#pragma unroll
    for (int ks = 0; ks < 2; ++ks) {
      bf16x8 ah[4], al[4], bh[4], bl[4];
#pragma unroll
      for (int m = 0; m < 4; ++m) {
        const int row = wr * 64 + m * 16 + (lane & 15);
        const int col8 = ks * 4 + (lane >> 4);
        const int off = row * BKk + ((col8 ^ (row & 7)) << 3);
        ah[m] = *(const bf16x8*)&lAhi[off];
        al[m] = *(const bf16x8*)&lAlo[off];
      }
#pragma unroll
      for (int n = 0; n < 4; ++n) {
        const int row = wc * 64 + n * 16 + (lane & 15);
        const int col8 = ks * 4 + (lane >> 4);
        const int off = row * BKk + ((col8 ^ (row & 7)) << 3);
        bh[n] = *(const bf16x8*)&lBhi[off];
        bl[n] = *(const bf16x8*)&lBlo[off];
      }
#pragma unroll
      for (int m = 0; m < 4; ++m)
#pragma unroll
        for (int n = 0; n < 4; ++n) {
          acc[m][n] = mfma16(ah[m], bh[n], acc[m][n]);
          acc[m][n] = mfma16(ah[m], bl[n], acc[m][n]);
          acc[m][n] = mfma16(al[m], bh[n], acc[m][n]);
        }
    }
  }
  const float scale = shape_ratio[0] * 0.044194173824159216f;  // 1/sqrt(512)
#pragma unroll
  for (int n = 0; n < 4; ++n) {
    const int kk = n0 + wc * 64 + n * 16 + (lane & 15);
#pragma unroll
    for (int m = 0; m < 4; ++m) {
      const int q = m0 + wr * 64 + m * 16 + ((lane >> 4) << 2);
#pragma unroll
      for (int r = 0; r < 4; ++r)
        Sout[((size_t)b * Sn + q + r) * Sn + kk] = acc[m][n][r] * scale;
    }
  }
}

// ---------------------------------------------------------------------------
// K3: row softmax over 2048 keys; fp32 in-place + bf16 copy for PV.
// (event_weight * event_flag is constant per row -> cancels in softmax.)
// ---------------------------------------------------------------------------
__global__ __launch_bounds__(256) void k3_softmax(float* __restrict__ Sm,
                                                  u16* __restrict__ Pb) {
  const int r = blockIdx.x;
  const int t = threadIdx.x;
  float* row = Sm + (size_t)r * Sn;
  float4 v0 = *(const float4*)(row + t * 8);
  float4 v1 = *(const float4*)(row + t * 8 + 4);
  float x[8] = {v0.x, v0.y, v0.z, v0.w, v1.x, v1.y, v1.z, v1.w};

  float m = -1e30f;
#pragma unroll
  for (int j = 0; j < 8; ++j) m = fmaxf(m, x[j]);
#pragma unroll
  for (int off = 32; off > 0; off >>= 1) m = fmaxf(m, __shfl_xor(m, off));
  __shared__ float red[8];
  if ((t & 63) == 0) red[t >> 6] = m;
  __syncthreads();
  m = fmaxf(fmaxf(red[0], red[1]), fmaxf(red[2], red[3]));

  float s = 0.f;
#pragma unroll
  for (int j = 0; j < 8; ++j) {
    x[j] = __expf(x[j] - m);
    s += x[j];
  }
#pragma unroll
  for (int off = 32; off > 0; off >>= 1) s += __shfl_xor(s, off);
  if ((t & 63) == 0) red[4 + (t >> 6)] = s;
  __syncthreads();
  s = (red[4] + red[5]) + (red[6] + red[7]);
  const float inv = 1.0f / s;

  us8 p;
#pragma unroll
  for (int j = 0; j < 8; ++j) {
    x[j] *= inv;
    p[j] = f2bf(x[j]);
  }
  float4 w0 = make_float4(x[0], x[1], x[2], x[3]);
  float4 w1 = make_float4(x[4], x[5], x[6], x[7]);
  *(float4*)(row + t * 8) = w0;
  *(float4*)(row + t * 8 + 4) = w1;
  *(us8*)(Pb + (size_t)r * Sn + t * 8) = p;
}

// ---------------------------------------------------------------------------
// K4: context[b] = attn_bf16[b] . V[b]  via Vt[b][h][k]; single bf16 pass.
// ---------------------------------------------------------------------------
__global__ __launch_bounds__(256) void k4_pv(
    const u16* __restrict__ P, const u16* __restrict__ Vt,
    float* __restrict__ Ctx) {
  __shared__ u16 lA[BM * BKk], lB[BM * BKk];
  const int t = threadIdx.x;
  const int lane = t & 63;
  const int wid = t >> 6;
  const int wr = wid >> 1, wc = wid & 1;
  const int b = blockIdx.z;
  const int n0 = blockIdx.x * BN;     // h tile
  const int m0 = blockIdx.y * BM;     // q tile
  const size_t prow0 = (size_t)b * Sn + m0;   // rows in P, stride Sn
  const size_t vrow0 = (size_t)b * Hn + n0;   // rows in Vt, stride Sn

  f32x4 acc[4][4];
  const f32x4 fz = {0.f, 0.f, 0.f, 0.f};
#pragma unroll
  for (int m = 0; m < 4; ++m)
#pragma unroll
    for (int n = 0; n < 4; ++n) acc[m][n] = fz;

  const int srow = lane >> 3;
  const int scol = ((lane & 7) ^ srow) << 3;

  for (int k0 = 0; k0 < Sn; k0 += BKk) {
    __syncthreads();
#pragma unroll
    for (int j = 0; j < 4; ++j) {
      const int ci = wid * 4 + j;
      const int row = ci * 8 + srow;
      g2l16(P + (prow0 + row) * Sn + k0 + scol, &lA[ci * 512]);
      g2l16(Vt + (vrow0 + row) * Sn + k0 + scol, &lB[ci * 512]);
    }
    __syncthreads();
#pragma unroll
    for (int ks = 0; ks < 2; ++ks) {
      bf16x8 af[4], bf[4];
#pragma unroll
      for (int m = 0; m < 4; ++m) {
        const int row = wr * 64 + m * 16 + (lane & 15);
        const int col8 = ks * 4 + (lane >> 4);
        af[m] = *(const bf16x8*)&lA[row * BKk + ((col8 ^ (row & 7)) << 3)];
      }
#pragma unroll
      for (int n = 0; n < 4; ++n) {
        const int row = wc * 64 + n * 16 + (lane & 15);
        const int col8 = ks * 4 + (lane >> 4);
        bf[n] = *(const bf16x8*)&lB[row * BKk + ((col8 ^ (row & 7)) << 3)];
      }
#pragma unroll
      for (int m = 0; m < 4; ++m)
#pragma unroll
        for (int n = 0; n < 4; ++n)
          acc[m][n] = mfma16(af[m], bf[n], acc[m][n]);
    }
  }
#pragma unroll
  for (int n = 0; n < 4; ++n) {
    const int h = n0 + wc * 64 + n * 16 + (lane & 15);
#pragma unroll
    for (int m = 0; m < 4; ++m) {
      const int q = m0 + wr * 64 + m * 16 + ((lane >> 4) << 2);
#pragma unroll
      for (int r = 0; r < 4; ++r)
        Ctx[((size_t)b * Sn + q + r) * Hn + h] = acc[m][n][r];
    }
  }
}

// ---------------------------------------------------------------------------
extern "C" void kernel_launch(void* const* d_in, const int* in_sizes, int n_in,
                              void* d_out, int out_size, void* d_ws, size_t ws_size,
                              hipStream_t stream) {
  const float* X  = (const float*)d_in[0];
  // d_in[1] = event_flag (cancels in softmax), d_in[2] = lengths (unused by ref)
  const float* Wq = (const float*)d_in[3];
  const float* bq = (const float*)d_in[4];
  const float* Wk = (const float*)d_in[5];
  const float* bk = (const float*)d_in[6];
  const float* Wv = (const float*)d_in[7];
  const float* bv = (const float*)d_in[8];
  // d_in[9] = event_weight (cancels in softmax)
  const float* shape_ratio = (const float*)d_in[10];

  float* ctx  = (float*)d_out;
  float* attn = ctx + (size_t)Bn * Sn * Hn;

  u16* ws = (u16*)d_ws;
  const size_t A = (size_t)Bn * Sn * Hn;   // 8,388,608 elements
  u16* Qhi = ws + 0 * A;
  u16* Qlo = ws + 1 * A;
  u16* Khi = ws + 2 * A;
  u16* Klo = ws + 3 * A;
  u16* Vt  = ws + 4 * A;
  u16* Pbf = ws;                           // aliases Qhi..Klo (dead after K2)

  k1_proj<<<dim3(12, 128), 256, 0, stream>>>(X, Wq, bq, Wk, bk, Wv, bv,
                                             Qhi, Qlo, Khi, Klo, Vt);
  k2_scores<<<dim3(16, 16, 8), 256, 0, stream>>>(Qhi, Qlo, Khi, Klo,
                                                 shape_ratio, attn);
  k3_softmax<<<dim3(Bn * Sn), 256, 0, stream>>>(attn, Pbf);
  k4_pv<<<dim3(4, 16, 8), 256, 0, stream>>>(Pbf, Vt, ctx);
}

// Round 2
// 308.832 us; speedup vs baseline: 1.1823x; 1.1823x over previous
//
#include <hip/hip_runtime.h>
#include <stdint.h>

// EventAwareAttention: B=8, S=2048, H=DK=512
// d_out = [context fp32 (8*2048*512)] ++ [attn fp32 (8*2048*2048)]
// d_ws: 5 * 8*2048*512 * 2 bytes = 83,886,080 bytes (~84 MB)
//   layout: Qhi | Qlo | Khi | Klo | Vt   (each 16384x512 bf16; Vt is [b][h][s])
//   attn-bf16 copy (16384x2048) aliases Qhi..Klo after they are dead.
// Xhi/Xlo/Whi/Wlo (37 MB) live temporarily in the attn region of d_out
// (fully rewritten by k2/k3 afterwards).

#define Bn 8
#define Sn 2048
#define Hn 512
#define BM 128
#define BN 128
#define BKk 64

typedef unsigned short u16;
typedef __attribute__((ext_vector_type(8))) short bf16x8;
typedef __attribute__((ext_vector_type(4))) float f32x4;
typedef __attribute__((ext_vector_type(8))) unsigned short us8;
typedef __attribute__((ext_vector_type(4))) unsigned short us4;

__device__ __forceinline__ u16 f2bf(float x) {
  union { float f; uint32_t u; } c;
  c.f = x;
  uint32_t u = c.u;
  return (u16)((u + 0x7FFFu + ((u >> 16) & 1u)) >> 16);   // RNE
}
__device__ __forceinline__ float bf2f(u16 h) {
  union { uint32_t u; float f; } c;
  c.u = ((uint32_t)h) << 16;
  return c.f;
}
__device__ __forceinline__ f32x4 mfma16(bf16x8 a, bf16x8 b, f32x4 c) {
  return __builtin_amdgcn_mfma_f32_16x16x32_bf16(a, b, c, 0, 0, 0);
}
__device__ __forceinline__ void g2l16(const void* g, void* l) {
  __builtin_amdgcn_global_load_lds(
      (const __attribute__((address_space(1))) void*)g,
      (__attribute__((address_space(3))) void*)l,
      16, 0, 0);
}

// ---------------------------------------------------------------------------
// K0: fp32 -> bf16 hi/lo split for X and W (one pass, memory-bound).
// grid (4096, 4): y=0 -> X (8.4M elems), y=1..3 -> Wq/Wk/Wv (256K each).
// ---------------------------------------------------------------------------
__global__ __launch_bounds__(256) void k0_split(
    const float* __restrict__ X,
    const float* __restrict__ Wq, const float* __restrict__ Wk,
    const float* __restrict__ Wv,
    u16* __restrict__ Xhi, u16* __restrict__ Xlo,
    u16* __restrict__ Whi, u16* __restrict__ Wlo) {
  const int y = blockIdx.y;
  const float* src;
  u16* hi;
  u16* lo;
  int n;
  if (y == 0) {
    src = X; hi = Xhi; lo = Xlo; n = 16384 * 512;
  } else {
    src = (y == 1) ? Wq : ((y == 2) ? Wk : Wv);
    hi = Whi + (size_t)(y - 1) * 512 * 512;
    lo = Wlo + (size_t)(y - 1) * 512 * 512;
    n = 512 * 512;
  }
  const int i = (blockIdx.x * 256 + threadIdx.x) * 8;
  if (i >= n) return;
  float4 v0 = *(const float4*)(src + i);
  float4 v1 = *(const float4*)(src + i + 4);
  float xs[8] = {v0.x, v0.y, v0.z, v0.w, v1.x, v1.y, v1.z, v1.w};
  us8 h, l;
#pragma unroll
  for (int j = 0; j < 8; ++j) {
    u16 hh = f2bf(xs[j]);
    h[j] = hh;
    l[j] = f2bf(xs[j] - bf2f(hh));
  }
  *(us8*)(hi + i) = h;
  *(us8*)(lo + i) = l;
}

// ---------------------------------------------------------------------------
// K1: QKV projection, pure-bf16 3-MFMA split GEMM (k2-style staging).
// C[M=16384, N=12*128] = X[M,512] . W[N,512]^T + bias
// Q/K stored as hi/lo bf16 pairs; V stored bf16 transposed: Vt[b][o][s].
// ---------------------------------------------------------------------------
__global__ __launch_bounds__(256) void k1_proj(
    const u16* __restrict__ Xhi, const u16* __restrict__ Xlo,
    const u16* __restrict__ Whi, const u16* __restrict__ Wlo,
    const float* __restrict__ bq, const float* __restrict__ bk,
    const float* __restrict__ bv,
    u16* __restrict__ Qhi, u16* __restrict__ Qlo,
    u16* __restrict__ Khi, u16* __restrict__ Klo,
    u16* __restrict__ Vt) {
  __shared__ u16 lAhi[BM * BKk], lAlo[BM * BKk];
  __shared__ u16 lBhi[BM * BKk], lBlo[BM * BKk];
  const int t = threadIdx.x;
  const int lane = t & 63;
  const int wid = t >> 6;
  const int wr = wid >> 1, wc = wid & 1;
  const int tn = blockIdx.x;          // 0..11: [Q0..3 K0..3 V0..3]
  const int m0 = blockIdx.y * BM;
  const int mat = tn >> 2;
  const int o0 = (tn & 3) * BN;
  const float* bsel = (mat == 0) ? bq : ((mat == 1) ? bk : bv);
  const size_t arow0 = (size_t)m0;                  // rows in X, stride Hn
  const size_t brow0 = (size_t)mat * 512 + o0;      // rows in W, stride Hn

  f32x4 acc[4][4];
  const f32x4 fz = {0.f, 0.f, 0.f, 0.f};
#pragma unroll
  for (int m = 0; m < 4; ++m)
#pragma unroll
    for (int n = 0; n < 4; ++n) acc[m][n] = fz;

  const int srow = lane >> 3;                     // row within 8-row chunk
  const int scol = ((lane & 7) ^ srow) << 3;      // pre-swizzled source col

  for (int k0 = 0; k0 < Hn; k0 += BKk) {
    __syncthreads();
#pragma unroll
    for (int j = 0; j < 4; ++j) {
      const int ci = wid * 4 + j;                 // 1KB chunk id 0..15
      const int row = ci * 8 + srow;
      const size_t ga = (arow0 + row) * Hn + k0 + scol;
      const size_t gb = (brow0 + row) * Hn + k0 + scol;
      g2l16(Xhi + ga, &lAhi[ci * 512]);
      g2l16(Xlo + ga, &lAlo[ci * 512]);
      g2l16(Whi + gb, &lBhi[ci * 512]);
      g2l16(Wlo + gb, &lBlo[ci * 512]);
    }
    __syncthreads();
#pragma unroll
    for (int ks = 0; ks < 2; ++ks) {
      bf16x8 ah[4], al[4], bh[4], bl[4];
#pragma unroll
      for (int m = 0; m < 4; ++m) {
        const int row = wr * 64 + m * 16 + (lane & 15);
        const int col8 = ks * 4 + (lane >> 4);
        const int off = row * BKk + ((col8 ^ (row & 7)) << 3);
        ah[m] = *(const bf16x8*)&lAhi[off];
        al[m] = *(const bf16x8*)&lAlo[off];
      }
#pragma unroll
      for (int n = 0; n < 4; ++n) {
        const int row = wc * 64 + n * 16 + (lane & 15);
        const int col8 = ks * 4 + (lane >> 4);
        const int off = row * BKk + ((col8 ^ (row & 7)) << 3);
        bh[n] = *(const bf16x8*)&lBhi[off];
        bl[n] = *(const bf16x8*)&lBlo[off];
      }
#pragma unroll
      for (int m = 0; m < 4; ++m)
#pragma unroll
        for (int n = 0; n < 4; ++n) {
          acc[m][n] = mfma16(ah[m], bh[n], acc[m][n]);
          acc[m][n] = mfma16(ah[m], bl[n], acc[m][n]);
          acc[m][n] = mfma16(al[m], bh[n], acc[m][n]);
        }
    }
  }
  // epilogue
#pragma unroll
  for (int n = 0; n < 4; ++n) {
    const int o = o0 + wc * 64 + n * 16 + (lane & 15);
    const float bias = bsel[o];
#pragma unroll
    for (int m = 0; m < 4; ++m) {
      const int ib = m0 + wr * 64 + m * 16 + ((lane >> 4) << 2);
      if (mat < 2) {
        u16* Hi = (mat == 0) ? Qhi : Khi;
        u16* Lo = (mat == 0) ? Qlo : Klo;
#pragma unroll
        for (int r = 0; r < 4; ++r) {
          const float v = acc[m][n][r] + bias;
          const u16 hh = f2bf(v);
          Hi[(size_t)(ib + r) * Hn + o] = hh;
          Lo[(size_t)(ib + r) * Hn + o] = f2bf(v - bf2f(hh));
        }
      } else {
        const int bb = ib >> 11, s = ib & 2047;
        us4 p;
#pragma unroll
        for (int r = 0; r < 4; ++r) p[r] = f2bf(acc[m][n][r] + bias);
        *(us4*)&Vt[((size_t)bb * Hn + o) * Sn + s] = p;
      }
    }
  }
}

// ---------------------------------------------------------------------------
// K2: scores[b] = (Q[b] . K[b]^T) * shape_ratio / sqrt(512), fp32 -> d_out.
// 3-MFMA split; staging via global_load_lds w=16 with pre-swizzled source.
// ---------------------------------------------------------------------------
__global__ __launch_bounds__(256) void k2_scores(
    const u16* __restrict__ Qhi, const u16* __restrict__ Qlo,
    const u16* __restrict__ Khi, const u16* __restrict__ Klo,
    const float* __restrict__ shape_ratio,
    float* __restrict__ Sout) {
  __shared__ u16 lAhi[BM * BKk], lAlo[BM * BKk];
  __shared__ u16 lBhi[BM * BKk], lBlo[BM * BKk];
  const int t = threadIdx.x;
  const int lane = t & 63;
  const int wid = t >> 6;
  const int wr = wid >> 1, wc = wid & 1;
  const int b = blockIdx.z;
  const int n0 = blockIdx.x * BN;
  const int m0 = blockIdx.y * BM;
  const size_t qrow0 = (size_t)b * Sn + m0;
  const size_t krow0 = (size_t)b * Sn + n0;

  f32x4 acc[4][4];
  const f32x4 fz = {0.f, 0.f, 0.f, 0.f};
#pragma unroll
  for (int m = 0; m < 4; ++m)
#pragma unroll
    for (int n = 0; n < 4; ++n) acc[m][n] = fz;

  const int srow = lane >> 3;                     // row within 8-row chunk
  const int scol = ((lane & 7) ^ srow) << 3;      // pre-swizzled source col

  for (int k0 = 0; k0 < Hn; k0 += BKk) {
    __syncthreads();
#pragma unroll
    for (int j = 0; j < 4; ++j) {
      const int ci = wid * 4 + j;                 // 1KB chunk id 0..15
      const int row = ci * 8 + srow;
      const size_t ga = (qrow0 + row) * Hn + k0 + scol;
      const size_t gb = (krow0 + row) * Hn + k0 + scol;
      g2l16(Qhi + ga, &lAhi[ci * 512]);
      g2l16(Qlo + ga, &lAlo[ci * 512]);
      g2l16(Khi + gb, &lBhi[ci * 512]);
      g2l16(Klo + gb, &lBlo[ci * 512]);
    }
    __syncthreads();
#pragma unroll
    for (int ks = 0; ks < 2; ++ks) {
      bf16x8 ah[4], al[4], bh[4], bl[4];
#pragma unroll
      for (int m = 0; m < 4; ++m) {
        const int row = wr * 64 + m * 16 + (lane & 15);
        const int col8 = ks * 4 + (lane >> 4);
        const int off = row * BKk + ((col8 ^ (row & 7)) << 3);
        ah[m] = *(const bf16x8*)&lAhi[off];
        al[m] = *(const bf16x8*)&lAlo[off];
      }
#pragma unroll
      for (int n = 0; n < 4; ++n) {
        const int row = wc * 64 + n * 16 + (lane & 15);
        const int col8 = ks * 4 + (lane >> 4);
        const int off = row * BKk + ((col8 ^ (row & 7)) << 3);
        bh[n] = *(const bf16x8*)&lBhi[off];
        bl[n] = *(const bf16x8*)&lBlo[off];
      }
#pragma unroll
      for (int m = 0; m < 4; ++m)
#pragma unroll
        for (int n = 0; n < 4; ++n) {
          acc[m][n] = mfma16(ah[m], bh[n], acc[m][n]);
          acc[m][n] = mfma16(ah[m], bl[n], acc[m][n]);
          acc[m][n] = mfma16(al[m], bh[n], acc[m][n]);
        }
    }
  }
  const float scale = shape_ratio[0] * 0.044194173824159216f;  // 1/sqrt(512)
#pragma unroll
  for (int n = 0; n < 4; ++n) {
    const int kk = n0 + wc * 64 + n * 16 + (lane & 15);
#pragma unroll
    for (int m = 0; m < 4; ++m) {
      const int q = m0 + wr * 64 + m * 16 + ((lane >> 4) << 2);
#pragma unroll
      for (int r = 0; r < 4; ++r)
        Sout[((size_t)b * Sn + q + r) * Sn + kk] = acc[m][n][r] * scale;
    }
  }
}

// ---------------------------------------------------------------------------
// K3: row softmax over 2048 keys; fp32 in-place + bf16 copy for PV.
// (event_weight * event_flag is constant per row -> cancels in softmax.)
// ---------------------------------------------------------------------------
__global__ __launch_bounds__(256) void k3_softmax(float* __restrict__ Sm,
                                                  u16* __restrict__ Pb) {
  const int r = blockIdx.x;
  const int t = threadIdx.x;
  float* row = Sm + (size_t)r * Sn;
  float4 v0 = *(const float4*)(row + t * 8);
  float4 v1 = *(const float4*)(row + t * 8 + 4);
  float x[8] = {v0.x, v0.y, v0.z, v0.w, v1.x, v1.y, v1.z, v1.w};

  float m = -1e30f;
#pragma unroll
  for (int j = 0; j < 8; ++j) m = fmaxf(m, x[j]);
#pragma unroll
  for (int off = 32; off > 0; off >>= 1) m = fmaxf(m, __shfl_xor(m, off));
  __shared__ float red[8];
  if ((t & 63) == 0) red[t >> 6] = m;
  __syncthreads();
  m = fmaxf(fmaxf(red[0], red[1]), fmaxf(red[2], red[3]));

  float s = 0.f;
#pragma unroll
  for (int j = 0; j < 8; ++j) {
    x[j] = __expf(x[j] - m);
    s += x[j];
  }
#pragma unroll
  for (int off = 32; off > 0; off >>= 1) s += __shfl_xor(s, off);
  if ((t & 63) == 0) red[4 + (t >> 6)] = s;
  __syncthreads();
  s = (red[4] + red[5]) + (red[6] + red[7]);
  const float inv = 1.0f / s;

  us8 p;
#pragma unroll
  for (int j = 0; j < 8; ++j) {
    x[j] *= inv;
    p[j] = f2bf(x[j]);
  }
  float4 w0 = make_float4(x[0], x[1], x[2], x[3]);
  float4 w1 = make_float4(x[4], x[5], x[6], x[7]);
  *(float4*)(row + t * 8) = w0;
  *(float4*)(row + t * 8 + 4) = w1;
  *(us8*)(Pb + (size_t)r * Sn + t * 8) = p;
}

// ---------------------------------------------------------------------------
// K4: context[b] = attn_bf16[b] . V[b]  via Vt[b][h][k]; single bf16 pass.
// ---------------------------------------------------------------------------
__global__ __launch_bounds__(256) void k4_pv(
    const u16* __restrict__ P, const u16* __restrict__ Vt,
    float* __restrict__ Ctx) {
  __shared__ u16 lA[BM * BKk], lB[BM * BKk];
  const int t = threadIdx.x;
  const int lane = t & 63;
  const int wid = t >> 6;
  const int wr = wid >> 1, wc = wid & 1;
  const int b = blockIdx.z;
  const int n0 = blockIdx.x * BN;     // h tile
  const int m0 = blockIdx.y * BM;     // q tile
  const size_t prow0 = (size_t)b * Sn + m0;   // rows in P, stride Sn
  const size_t vrow0 = (size_t)b * Hn + n0;   // rows in Vt, stride Sn

  f32x4 acc[4][4];
  const f32x4 fz = {0.f, 0.f, 0.f, 0.f};
#pragma unroll
  for (int m = 0; m < 4; ++m)
#pragma unroll
    for (int n = 0; n < 4; ++n) acc[m][n] = fz;

  const int srow = lane >> 3;
  const int scol = ((lane & 7) ^ srow) << 3;

  for (int k0 = 0; k0 < Sn; k0 += BKk) {
    __syncthreads();
#pragma unroll
    for (int j = 0; j < 4; ++j) {
      const int ci = wid * 4 + j;
      const int row = ci * 8 + srow;
      g2l16(P + (prow0 + row) * Sn + k0 + scol, &lA[ci * 512]);
      g2l16(Vt + (vrow0 + row) * Sn + k0 + scol, &lB[ci * 512]);
    }
    __syncthreads();
#pragma unroll
    for (int ks = 0; ks < 2; ++ks) {
      bf16x8 af[4], bf[4];
#pragma unroll
      for (int m = 0; m < 4; ++m) {
        const int row = wr * 64 + m * 16 + (lane & 15);
        const int col8 = ks * 4 + (lane >> 4);
        af[m] = *(const bf16x8*)&lA[row * BKk + ((col8 ^ (row & 7)) << 3)];
      }
#pragma unroll
      for (int n = 0; n < 4; ++n) {
        const int row = wc * 64 + n * 16 + (lane & 15);
        const int col8 = ks * 4 + (lane >> 4);
        bf[n] = *(const bf16x8*)&lB[row * BKk + ((col8 ^ (row & 7)) << 3)];
      }
#pragma unroll
      for (int m = 0; m < 4; ++m)
#pragma unroll
        for (int n = 0; n < 4; ++n)
          acc[m][n] = mfma16(af[m], bf[n], acc[m][n]);
    }
  }
#pragma unroll
  for (int n = 0; n < 4; ++n) {
    const int h = n0 + wc * 64 + n * 16 + (lane & 15);
#pragma unroll
    for (int m = 0; m < 4; ++m) {
      const int q = m0 + wr * 64 + m * 16 + ((lane >> 4) << 2);
#pragma unroll
      for (int r = 0; r < 4; ++r)
        Ctx[((size_t)b * Sn + q + r) * Hn + h] = acc[m][n][r];
    }
  }
}

// ---------------------------------------------------------------------------
extern "C" void kernel_launch(void* const* d_in, const int* in_sizes, int n_in,
                              void* d_out, int out_size, void* d_ws, size_t ws_size,
                              hipStream_t stream) {
  const float* X  = (const float*)d_in[0];
  // d_in[1] = event_flag (cancels in softmax), d_in[2] = lengths (unused by ref)
  const float* Wq = (const float*)d_in[3];
  const float* bq = (const float*)d_in[4];
  const float* Wk = (const float*)d_in[5];
  const float* bk = (const float*)d_in[6];
  const float* Wv = (const float*)d_in[7];
  const float* bv = (const float*)d_in[8];
  // d_in[9] = event_weight (cancels in softmax)
  const float* shape_ratio = (const float*)d_in[10];

  float* ctx  = (float*)d_out;
  float* attn = ctx + (size_t)Bn * Sn * Hn;

  u16* ws = (u16*)d_ws;
  const size_t A = (size_t)Bn * Sn * Hn;   // 8,388,608 elements
  u16* Qhi = ws + 0 * A;
  u16* Qlo = ws + 1 * A;
  u16* Khi = ws + 2 * A;
  u16* Klo = ws + 3 * A;
  u16* Vt  = ws + 4 * A;
  u16* Pbf = ws;                           // aliases Qhi..Klo (dead after K2)

  // X/W hi-lo splits live in the (not-yet-written) attn region of d_out.
  u16* Xhi = (u16*)attn;                   // 8.4M u16
  u16* Xlo = Xhi + A;
  u16* Whi = Xlo + A;                      // 3*512*512 u16
  u16* Wlo = Whi + (size_t)3 * 512 * 512;

  k0_split<<<dim3(4096, 4), 256, 0, stream>>>(X, Wq, Wk, Wv, Xhi, Xlo, Whi, Wlo);
  k1_proj<<<dim3(12, 128), 256, 0, stream>>>(Xhi, Xlo, Whi, Wlo, bq, bk, bv,
                                             Qhi, Qlo, Khi, Klo, Vt);
  k2_scores<<<dim3(16, 16, 8), 256, 0, stream>>>(Qhi, Qlo, Khi, Klo,
                                                 shape_ratio, attn);
  k3_softmax<<<dim3(Bn * Sn), 256, 0, stream>>>(attn, Pbf);
  k4_pv<<<dim3(4, 16, 8), 256, 0, stream>>>(Pbf, Vt, ctx);
}

// Round 3
// 207.758 us; speedup vs baseline: 1.7574x; 1.4865x over previous
//
#include <hip/hip_runtime.h>
#include <stdint.h>

// EventAwareAttention: B=8, S=2048, H=DK=512
// d_out = [context fp32 (8*2048*512)] ++ [attn fp32 (8*2048*2048)]
// All GEMMs single-pass fp16 (precision analysis: score err ~1e-3 RMS,
// attn err ~1.5e-4 << 2%-of-absmax threshold).
// ws (5A u16 = 84 MB): [0,A) Xf16 | [A,A+W3) Wf16 | then Qf16,Kf16 | [4A,5A) Vt
//   P-fp16 [0,4A) overlays X/W/Q/K after k2 (they are dead).
// Scores fp16 are written interleaved into d_out's attn region: row r's 2048
// fp16 occupy the first 4096 B of row r's 8192 B fp32 slot (self-contained,
// race-free: k3 block r reads its own row to regs, syncs, overwrites).

#define Bn 8
#define Sn 2048
#define Hn 512
#define BM 128
#define BN 128
#define BKk 64

typedef unsigned short u16;
typedef _Float16 h16;
typedef __attribute__((ext_vector_type(8))) _Float16 f16x8;
typedef __attribute__((ext_vector_type(4))) _Float16 f16x4;
typedef __attribute__((ext_vector_type(4))) float f32x4;
typedef __attribute__((ext_vector_type(8))) unsigned short us8;

__device__ __forceinline__ f32x4 mfma16h(f16x8 a, f16x8 b, f32x4 c) {
  return __builtin_amdgcn_mfma_f32_16x16x32_f16(a, b, c, 0, 0, 0);
}
__device__ __forceinline__ void g2l16(const void* g, void* l) {
  __builtin_amdgcn_global_load_lds(
      (const __attribute__((address_space(1))) void*)g,
      (__attribute__((address_space(3))) void*)l,
      16, 0, 0);
}

// ---------------------------------------------------------------------------
// K0: fp32 -> fp16 for X and Wq/Wk/Wv (memory-bound one-pass).
// grid (4096, 4): y=0 -> X, y=1..3 -> Wq/Wk/Wv.
// ---------------------------------------------------------------------------
__global__ __launch_bounds__(256) void k0_cvt(
    const float* __restrict__ X,
    const float* __restrict__ Wq, const float* __restrict__ Wk,
    const float* __restrict__ Wv,
    h16* __restrict__ Xf, h16* __restrict__ Wf) {
  const int y = blockIdx.y;
  const float* src;
  h16* dst;
  int n;
  if (y == 0) {
    src = X; dst = Xf; n = 16384 * 512;
  } else {
    src = (y == 1) ? Wq : ((y == 2) ? Wk : Wv);
    dst = Wf + (size_t)(y - 1) * 512 * 512;
    n = 512 * 512;
  }
  const int i = (blockIdx.x * 256 + threadIdx.x) * 8;
  if (i >= n) return;
  float4 v0 = *(const float4*)(src + i);
  float4 v1 = *(const float4*)(src + i + 4);
  f16x8 h;
  h[0] = (h16)v0.x; h[1] = (h16)v0.y; h[2] = (h16)v0.z; h[3] = (h16)v0.w;
  h[4] = (h16)v1.x; h[5] = (h16)v1.y; h[6] = (h16)v1.z; h[7] = (h16)v1.w;
  *(f16x8*)(dst + i) = h;
}

// ---------------------------------------------------------------------------
// K1: QKV projection, single fp16 GEMM. C[16384, 12*128] = Xf . Wf^T + bias
// Q,K row-major fp16; V transposed fp16: Vt[b][o][s].
// ---------------------------------------------------------------------------
__global__ __launch_bounds__(256) void k1_proj(
    const h16* __restrict__ Xf, const h16* __restrict__ Wf,
    const float* __restrict__ bq, const float* __restrict__ bk,
    const float* __restrict__ bv,
    h16* __restrict__ Qf, h16* __restrict__ Kf, h16* __restrict__ Vt) {
  __shared__ h16 lA[BM * BKk], lB[BM * BKk];
  const int t = threadIdx.x;
  const int lane = t & 63;
  const int wid = t >> 6;
  const int wr = wid >> 1, wc = wid & 1;
  const int tn = blockIdx.x;          // 0..11: [Q0..3 K0..3 V0..3]
  const int m0 = blockIdx.y * BM;
  const int mat = tn >> 2;
  const int o0 = (tn & 3) * BN;
  const float* bsel = (mat == 0) ? bq : ((mat == 1) ? bk : bv);
  const size_t arow0 = (size_t)m0;
  const size_t brow0 = (size_t)mat * 512 + o0;

  f32x4 acc[4][4];
  const f32x4 fz = {0.f, 0.f, 0.f, 0.f};
#pragma unroll
  for (int m = 0; m < 4; ++m)
#pragma unroll
    for (int n = 0; n < 4; ++n) acc[m][n] = fz;

  const int srow = lane >> 3;
  const int scol = ((lane & 7) ^ srow) << 3;

  for (int k0 = 0; k0 < Hn; k0 += BKk) {
    __syncthreads();
#pragma unroll
    for (int j = 0; j < 4; ++j) {
      const int ci = wid * 4 + j;                 // 1KB chunk id 0..15
      const int row = ci * 8 + srow;
      g2l16(Xf + (arow0 + row) * Hn + k0 + scol, &lA[ci * 512]);
      g2l16(Wf + (brow0 + row) * Hn + k0 + scol, &lB[ci * 512]);
    }
    __syncthreads();
#pragma unroll
    for (int ks = 0; ks < 2; ++ks) {
      f16x8 af[4], bf[4];
#pragma unroll
      for (int m = 0; m < 4; ++m) {
        const int row = wr * 64 + m * 16 + (lane & 15);
        const int col8 = ks * 4 + (lane >> 4);
        af[m] = *(const f16x8*)&lA[row * BKk + ((col8 ^ (row & 7)) << 3)];
      }
#pragma unroll
      for (int n = 0; n < 4; ++n) {
        const int row = wc * 64 + n * 16 + (lane & 15);
        const int col8 = ks * 4 + (lane >> 4);
        bf[n] = *(const f16x8*)&lB[row * BKk + ((col8 ^ (row & 7)) << 3)];
      }
#pragma unroll
      for (int m = 0; m < 4; ++m)
#pragma unroll
        for (int n = 0; n < 4; ++n)
          acc[m][n] = mfma16h(af[m], bf[n], acc[m][n]);
    }
  }
  // epilogue
#pragma unroll
  for (int n = 0; n < 4; ++n) {
    const int o = o0 + wc * 64 + n * 16 + (lane & 15);
    const float bias = bsel[o];
#pragma unroll
    for (int m = 0; m < 4; ++m) {
      const int ib = m0 + wr * 64 + m * 16 + ((lane >> 4) << 2);
      if (mat < 2) {
        h16* Dst = (mat == 0) ? Qf : Kf;
#pragma unroll
        for (int r = 0; r < 4; ++r)
          Dst[(size_t)(ib + r) * Hn + o] = (h16)(acc[m][n][r] + bias);
      } else {
        const int bb = ib >> 11, s = ib & 2047;
        f16x4 p;
#pragma unroll
        for (int r = 0; r < 4; ++r) p[r] = (h16)(acc[m][n][r] + bias);
        *(f16x4*)&Vt[((size_t)bb * Hn + o) * Sn + s] = p;
      }
    }
  }
}

// ---------------------------------------------------------------------------
// K2: scores[b] = (Q[b].K[b]^T) * shape_ratio/sqrt(512), fp16 ->
// interleaved into attn region (row r's fp16 at byte offset 8192*r).
// ---------------------------------------------------------------------------
__global__ __launch_bounds__(256) void k2_scores(
    const h16* __restrict__ Qf, const h16* __restrict__ Kf,
    const float* __restrict__ shape_ratio,
    h16* __restrict__ S16) {          // u16-view of attn region, row stride 4096
  __shared__ h16 lA[BM * BKk], lB[BM * BKk];
  const int t = threadIdx.x;
  const int lane = t & 63;
  const int wid = t >> 6;
  const int wr = wid >> 1, wc = wid & 1;
  const int b = blockIdx.z;
  const int n0 = blockIdx.x * BN;
  const int m0 = blockIdx.y * BM;
  const size_t qrow0 = (size_t)b * Sn + m0;
  const size_t krow0 = (size_t)b * Sn + n0;

  f32x4 acc[4][4];
  const f32x4 fz = {0.f, 0.f, 0.f, 0.f};
#pragma unroll
  for (int m = 0; m < 4; ++m)
#pragma unroll
    for (int n = 0; n < 4; ++n) acc[m][n] = fz;

  const int srow = lane >> 3;
  const int scol = ((lane & 7) ^ srow) << 3;

  for (int k0 = 0; k0 < Hn; k0 += BKk) {
    __syncthreads();
#pragma unroll
    for (int j = 0; j < 4; ++j) {
      const int ci = wid * 4 + j;
      const int row = ci * 8 + srow;
      g2l16(Qf + (qrow0 + row) * Hn + k0 + scol, &lA[ci * 512]);
      g2l16(Kf + (krow0 + row) * Hn + k0 + scol, &lB[ci * 512]);
    }
    __syncthreads();
#pragma unroll
    for (int ks = 0; ks < 2; ++ks) {
      f16x8 af[4], bf[4];
#pragma unroll
      for (int m = 0; m < 4; ++m) {
        const int row = wr * 64 + m * 16 + (lane & 15);
        const int col8 = ks * 4 + (lane >> 4);
        af[m] = *(const f16x8*)&lA[row * BKk + ((col8 ^ (row & 7)) << 3)];
      }
#pragma unroll
      for (int n = 0; n < 4; ++n) {
        const int row = wc * 64 + n * 16 + (lane & 15);
        const int col8 = ks * 4 + (lane >> 4);
        bf[n] = *(const f16x8*)&lB[row * BKk + ((col8 ^ (row & 7)) << 3)];
      }
#pragma unroll
      for (int m = 0; m < 4; ++m)
#pragma unroll
        for (int n = 0; n < 4; ++n)
          acc[m][n] = mfma16h(af[m], bf[n], acc[m][n]);
    }
  }
  const float scale = shape_ratio[0] * 0.044194173824159216f;  // 1/sqrt(512)
#pragma unroll
  for (int n = 0; n < 4; ++n) {
    const int kk = n0 + wc * 64 + n * 16 + (lane & 15);
#pragma unroll
    for (int m = 0; m < 4; ++m) {
      const int q = m0 + wr * 64 + m * 16 + ((lane >> 4) << 2);
#pragma unroll
      for (int r = 0; r < 4; ++r)
        S16[((size_t)b * Sn + q + r) * 4096 + kk] = (h16)(acc[m][n][r] * scale);
    }
  }
}

// ---------------------------------------------------------------------------
// K3: row softmax. Reads fp16 scores from the row's own slot, writes fp32
// attn over it (regs -> sync -> store) + fp16 P to ws.
// ---------------------------------------------------------------------------
__global__ __launch_bounds__(256) void k3_softmax(float* __restrict__ Sm,
                                                  h16* __restrict__ Pf) {
  const int r = blockIdx.x;
  const int t = threadIdx.x;
  float* row = Sm + (size_t)r * Sn;
  const h16* srow = (const h16*)row;           // fp16 scores, first 4 KB
  f16x8 hv = *(const f16x8*)(srow + t * 8);
  float x[8];
#pragma unroll
  for (int j = 0; j < 8; ++j) x[j] = (float)hv[j];

  float m = -1e30f;
#pragma unroll
  for (int j = 0; j < 8; ++j) m = fmaxf(m, x[j]);
#pragma unroll
  for (int off = 32; off > 0; off >>= 1) m = fmaxf(m, __shfl_xor(m, off));
  __shared__ float red[8];
  if ((t & 63) == 0) red[t >> 6] = m;
  __syncthreads();
  m = fmaxf(fmaxf(red[0], red[1]), fmaxf(red[2], red[3]));

  float s = 0.f;
#pragma unroll
  for (int j = 0; j < 8; ++j) {
    x[j] = __expf(x[j] - m);
    s += x[j];
  }
#pragma unroll
  for (int off = 32; off > 0; off >>= 1) s += __shfl_xor(s, off);
  if ((t & 63) == 0) red[4 + (t >> 6)] = s;
  __syncthreads();
  s = (red[4] + red[5]) + (red[6] + red[7]);
  const float inv = 1.0f / s;

  f16x8 p;
#pragma unroll
  for (int j = 0; j < 8; ++j) {
    x[j] *= inv;
    p[j] = (h16)x[j];
  }
  __syncthreads();                              // all reads done before fp32 overwrite
  float4 w0 = make_float4(x[0], x[1], x[2], x[3]);
  float4 w1 = make_float4(x[4], x[5], x[6], x[7]);
  *(float4*)(row + t * 8) = w0;
  *(float4*)(row + t * 8 + 4) = w1;
  *(f16x8*)(Pf + (size_t)r * Sn + t * 8) = p;
}

// ---------------------------------------------------------------------------
// K4: context[b] = P[b] . V[b] via Vt[b][h][k]; fp16 MFMA.
// ---------------------------------------------------------------------------
__global__ __launch_bounds__(256) void k4_pv(
    const h16* __restrict__ P, const h16* __restrict__ Vt,
    float* __restrict__ Ctx) {
  __shared__ h16 lA[BM * BKk], lB[BM * BKk];
  const int t = threadIdx.x;
  const int lane = t & 63;
  const int wid = t >> 6;
  const int wr = wid >> 1, wc = wid & 1;
  const int b = blockIdx.z;
  const int n0 = blockIdx.x * BN;     // h tile
  const int m0 = blockIdx.y * BM;     // q tile
  const size_t prow0 = (size_t)b * Sn + m0;   // rows in P, stride Sn
  const size_t vrow0 = (size_t)b * Hn + n0;   // rows in Vt, stride Sn

  f32x4 acc[4][4];
  const f32x4 fz = {0.f, 0.f, 0.f, 0.f};
#pragma unroll
  for (int m = 0; m < 4; ++m)
#pragma unroll
    for (int n = 0; n < 4; ++n) acc[m][n] = fz;

  const int srow = lane >> 3;
  const int scol = ((lane & 7) ^ srow) << 3;

  for (int k0 = 0; k0 < Sn; k0 += BKk) {
    __syncthreads();
#pragma unroll
    for (int j = 0; j < 4; ++j) {
      const int ci = wid * 4 + j;
      const int row = ci * 8 + srow;
      g2l16(P + (prow0 + row) * Sn + k0 + scol, &lA[ci * 512]);
      g2l16(Vt + (vrow0 + row) * Sn + k0 + scol, &lB[ci * 512]);
    }
    __syncthreads();
#pragma unroll
    for (int ks = 0; ks < 2; ++ks) {
      f16x8 af[4], bf[4];
#pragma unroll
      for (int m = 0; m < 4; ++m) {
        const int row = wr * 64 + m * 16 + (lane & 15);
        const int col8 = ks * 4 + (lane >> 4);
        af[m] = *(const f16x8*)&lA[row * BKk + ((col8 ^ (row & 7)) << 3)];
      }
#pragma unroll
      for (int n = 0; n < 4; ++n) {
        const int row = wc * 64 + n * 16 + (lane & 15);
        const int col8 = ks * 4 + (lane >> 4);
        bf[n] = *(const f16x8*)&lB[row * BKk + ((col8 ^ (row & 7)) << 3)];
      }
#pragma unroll
      for (int m = 0; m < 4; ++m)
#pragma unroll
        for (int n = 0; n < 4; ++n)
          acc[m][n] = mfma16h(af[m], bf[n], acc[m][n]);
    }
  }
#pragma unroll
  for (int n = 0; n < 4; ++n) {
    const int h = n0 + wc * 64 + n * 16 + (lane & 15);
#pragma unroll
    for (int m = 0; m < 4; ++m) {
      const int q = m0 + wr * 64 + m * 16 + ((lane >> 4) << 2);
#pragma unroll
      for (int r = 0; r < 4; ++r)
        Ctx[((size_t)b * Sn + q + r) * Hn + h] = acc[m][n][r];
    }
  }
}

// ---------------------------------------------------------------------------
extern "C" void kernel_launch(void* const* d_in, const int* in_sizes, int n_in,
                              void* d_out, int out_size, void* d_ws, size_t ws_size,
                              hipStream_t stream) {
  const float* X  = (const float*)d_in[0];
  // d_in[1] = event_flag (cancels in softmax), d_in[2] = lengths (unused by ref)
  const float* Wq = (const float*)d_in[3];
  const float* bq = (const float*)d_in[4];
  const float* Wk = (const float*)d_in[5];
  const float* bk = (const float*)d_in[6];
  const float* Wv = (const float*)d_in[7];
  const float* bv = (const float*)d_in[8];
  // d_in[9] = event_weight (cancels in softmax)
  const float* shape_ratio = (const float*)d_in[10];

  float* ctx  = (float*)d_out;
  float* attn = ctx + (size_t)Bn * Sn * Hn;

  h16* ws = (h16*)d_ws;
  const size_t A = (size_t)Bn * Sn * Hn;   // 8,388,608 elements
  const size_t W3 = (size_t)3 * 512 * 512; // 786,432
  h16* Xf = ws;                            // [0, A)          dead after k1... k1 reads it
  h16* Wf = ws + A;                        // [A, A+W3)
  h16* Qf = ws + A + W3;                   // [A+W3, 2A+W3)
  h16* Kf = ws + 2 * A + W3;               // [2A+W3, 3A+W3)
  h16* Vt = ws + 4 * A;                    // [4A, 5A)
  h16* Pf = ws;                            // [0, 4A) overlays X/W/Q/K (dead after k2)

  k0_cvt<<<dim3(4096, 4), 256, 0, stream>>>(X, Wq, Wk, Wv, Xf, Wf);
  k1_proj<<<dim3(12, 128), 256, 0, stream>>>(Xf, Wf, bq, bk, bv, Qf, Kf, Vt);
  k2_scores<<<dim3(16, 16, 8), 256, 0, stream>>>(Qf, Kf, shape_ratio, (h16*)attn);
  k3_softmax<<<dim3(Bn * Sn), 256, 0, stream>>>(attn, Pf);
  k4_pv<<<dim3(4, 16, 8), 256, 0, stream>>>(Pf, Vt, ctx);
}